// Round 11
// baseline (400.989 us; speedup 1.0000x reference)
//
#include <hip/hip_runtime.h>
#include <math.h>

#define N_ATOMS 20000
#define N_EDGES 200000
#define CH 64
#define NB 8
#define NK 11
#define ATOMS_PER_BLOCK 4
#define ATOM_BLOCKS (N_ATOMS / ATOMS_PER_BLOCK)   // 5000
#define COPY_F4 (N_EDGES * CH / 4)                // 3,200,000 float4
#define COPY_PER_BLOCK 1024                       // 256 threads x 4 float4
#define COPY_BLOCKS (COPY_F4 / COPY_PER_BLOCK)    // 3125

#define WSTRIDE 44   // dwords per lane of packed f16 weights (88 halves)

// epilogue kernels: atoms per wave / blocks (4 waves per block)
#define E0_APW 64
#define E0_BLOCKS 79    // 79*4*64  = 20224 >= 20000
#define E1_APW 16
#define E1_BLOCKS 313   // 313*4*16 = 20032 >= 20000
#define E2_APW 8
#define E2_BLOCKS 625   // 625*4*8  = 20000 exact

typedef _Float16 h2 __attribute__((ext_vector_type(2)));   // fdot2 operand type
typedef __fp16  p2 __attribute__((ext_vector_type(2)));    // cvt_pkrtz result type

union F2H { float f; h2 h; p2 p; unsigned int u; };

// ---------------------------------------------------------------
// Kernel 1: histogram of idx_i
__global__ __launch_bounds__(256) void hist_kernel(
    const int* __restrict__ idx_i, int* __restrict__ counts)
{
    int e = blockIdx.x * blockDim.x + threadIdx.x;
    if (e >= N_EDGES) return;
    atomicAdd(&counts[idx_i[e]], 1);
}

// ---------------------------------------------------------------
// Kernel 2: exclusive scan (single 1024-thread block)
__global__ __launch_bounds__(1024) void scan_kernel(
    const int* __restrict__ counts, int* __restrict__ offsets,
    int* __restrict__ cursor)
{
    __shared__ int part[1024];
    const int CHUNK = 20;  // 1024*20 = 20480 >= 20000
    int t = threadIdx.x;
    int beg = t * CHUNK;
    int s = 0;
    for (int k = 0; k < CHUNK; ++k) {
        int idx = beg + k;
        if (idx < N_ATOMS) s += counts[idx];
    }
    part[t] = s;
    __syncthreads();
    for (int off = 1; off < 1024; off <<= 1) {
        int v = (t >= off) ? part[t - off] : 0;
        __syncthreads();
        part[t] += v;
        __syncthreads();
    }
    int run = part[t] - s;
    for (int k = 0; k < CHUNK; ++k) {
        int idx = beg + k;
        if (idx < N_ATOMS) {
            offsets[idx] = run;
            cursor[idx] = run;
            run += counts[idx];
        }
    }
    if (t == 0) offsets[N_ATOMS] = N_EDGES;
}

// ---------------------------------------------------------------
// Kernel 3: scatter into CSR order, computing geometry on the fly
__global__ __launch_bounds__(256) void scatter_geom_kernel(
    const float* __restrict__ rij, const int* __restrict__ idx_i,
    const int* __restrict__ idx_j, int* __restrict__ cursor,
    int* __restrict__ jlist, float4* __restrict__ ge4)
{
    int e = blockIdx.x * blockDim.x + threadIdx.x;
    if (e >= N_EDGES) return;

    float rx = rij[e * 3 + 0];
    float ry = rij[e * 3 + 1];
    float rz = rij[e * 3 + 2];
    float d = sqrtf(rx * rx + ry * ry + rz * rz);
    float inv = 1.0f / (d + 1e-12f);

    float dc = fminf(d, 5.0f);
    float fcut = 0.5f * (cosf(3.14159265358979323846f * dc * 0.2f) + 1.0f);

    float rbf[NB];
#pragma unroll
    for (int b = 0; b < NB; ++b) {
        float mu = (5.0f / 7.0f) * (float)b;
        float t = d - mu;
        rbf[b] = expf(-2.0f * t * t) * fcut;
    }

    int p = atomicAdd(&cursor[idx_i[e]], 1);
    jlist[p] = idx_j[e];
    ge4[p * 3 + 0] = make_float4(rx * inv, ry * inv, rz * inv, rbf[0]);
    ge4[p * 3 + 1] = make_float4(rbf[1], rbf[2], rbf[3], rbf[4]);
    ge4[p * 3 + 2] = make_float4(rbf[5], rbf[6], rbf[7], 0.f);
}

// ---------------------------------------------------------------
// Kernel 4: edge gather/accumulate ONLY. Writes scaled accumulators
// into the out regions in per-atom transposed layout:
//   out0[n*64 + cc]              = a0
//   out1[n*192 + x*64 + cc]      = a1[x]      (x = 0..2)
//   out2[n*576 + q*64 + cc]      = a2[q]      (q = 0..8)
// (epilogue kernels read these wave-uniformly and overwrite in place)
// Blocks >= ATOM_BLOCKS copy edge0 -> oute (overlaps with compute).
__global__ __launch_bounds__(256) void edge_acc_kernel(
    const float* __restrict__ node0, const float* __restrict__ node1,
    const float* __restrict__ node2,
    const int* __restrict__ jlist, const int* __restrict__ offsets,
    const float4* __restrict__ ge4, const float* __restrict__ rbf_w,
    float* __restrict__ out0, float* __restrict__ out1, float* __restrict__ out2,
    const float4* __restrict__ edge0_in, float4* __restrict__ edge0_out)
{
    int bid = blockIdx.x;

    if (bid >= ATOM_BLOCKS) {
        size_t base = (size_t)(bid - ATOM_BLOCKS) * COPY_PER_BLOCK;
#pragma unroll
        for (int k = 0; k < 4; ++k)
            edge0_out[base + k * 256 + threadIdx.x] =
                edge0_in[base + k * 256 + threadIdx.x];
        return;
    }

    __shared__ __align__(16) float wlds[CH * WSTRIDE]; // 11.0 KB packed f16 weights

    int wv = threadIdx.x >> 6;
    int c = threadIdx.x & 63;

    // stage f16-packed weights once per block
    {
        for (int kd = wv; kd < WSTRIDE; kd += 4) {
            int k = kd >> 2, j = kd & 3;
            float w0 = rbf_w[(k * NB + 2 * j) * CH + c];
            float w1 = rbf_w[(k * NB + 2 * j + 1) * CH + c];
            F2H u;
            u.p = __builtin_amdgcn_cvt_pkrtz(w0, w1);
            wlds[c * WSTRIDE + kd] = u.f;
        }
    }
    __syncthreads();

    int n = bid * ATOMS_PER_BLOCK + wv;   // N_ATOMS % 4 == 0

    float a0 = 0.f;
    float a1[3] = {0.f, 0.f, 0.f};
    float a2[9] = {0.f, 0.f, 0.f, 0.f, 0.f, 0.f, 0.f, 0.f, 0.f};

    int beg = offsets[n];
    int end = offsets[n + 1];

    float4 g0, g1v, g2v;
    float h0 = 0.f, h1[3] = {0.f, 0.f, 0.f};
    float h2v[9] = {0.f, 0.f, 0.f, 0.f, 0.f, 0.f, 0.f, 0.f, 0.f};
    int jnx = 0;

    if (beg < end) {
        int j = jlist[beg];
        g0 = ge4[beg * 3 + 0];
        g1v = ge4[beg * 3 + 1];
        g2v = ge4[beg * 3 + 2];
        h0 = node0[(size_t)j * CH + c];
#pragma unroll
        for (int x = 0; x < 3; ++x) h1[x] = node1[((size_t)j * CH + c) * 3 + x];
#pragma unroll
        for (int q = 0; q < 9; ++q) h2v[q] = node2[((size_t)j * CH + c) * 9 + q];
        jnx = (beg + 1 < end) ? jlist[beg + 1] : 0;
    }

    for (int p = beg; p < end; ++p) {
        float rh[3] = {g0.x, g0.y, g0.z};
        float rbf[NB] = {g0.w, g1v.x, g1v.y, g1v.z, g1v.w, g2v.x, g2v.y, g2v.z};
        float ch0 = h0;
        float ch1[3] = {h1[0], h1[1], h1[2]};
        float ch2[9];
#pragma unroll
        for (int q = 0; q < 9; ++q) ch2[q] = h2v[q];

        if (p + 1 < end) {
            int j2 = jnx;
            g0 = ge4[(p + 1) * 3 + 0];
            g1v = ge4[(p + 1) * 3 + 1];
            g2v = ge4[(p + 1) * 3 + 2];
            h0 = node0[(size_t)j2 * CH + c];
#pragma unroll
            for (int x = 0; x < 3; ++x) h1[x] = node1[((size_t)j2 * CH + c) * 3 + x];
#pragma unroll
            for (int q = 0; q < 9; ++q) h2v[q] = node2[((size_t)j2 * CH + c) * 9 + q];
            jnx = (p + 2 < end) ? jlist[p + 2] : 0;
        }

        h2 rb[4];
        {
            F2H u;
            u.p = __builtin_amdgcn_cvt_pkrtz(rbf[0], rbf[1]); rb[0] = u.h;
            u.p = __builtin_amdgcn_cvt_pkrtz(rbf[2], rbf[3]); rb[1] = u.h;
            u.p = __builtin_amdgcn_cvt_pkrtz(rbf[4], rbf[5]); rb[2] = u.h;
            u.p = __builtin_amdgcn_cvt_pkrtz(rbf[6], rbf[7]); rb[3] = u.h;
        }

        // fc from LDS: 11 x ds_read_b128 + 44 fdot2 (opaque lane index
        // prevents LICM hoist -> the R3-R7 spill/remat trap)
        int cop = c;
        asm volatile("" : "+v"(cop));
        const float4* wp4 = reinterpret_cast<const float4*>(&wlds[cop * WSTRIDE]);

        float fc[NK];
#pragma unroll
        for (int k = 0; k < NK; ++k) {
            float4 w = wp4[k];
            F2H u0, u1_, u2, u3;
            u0.f = w.x; u1_.f = w.y; u2.f = w.z; u3.f = w.w;
            float s = __builtin_amdgcn_fdot2(rb[0], u0.h, 0.f, false);
            s = __builtin_amdgcn_fdot2(rb[1], u1_.h, s, false);
            s = __builtin_amdgcn_fdot2(rb[2], u2.h, s, false);
            fc[k] = __builtin_amdgcn_fdot2(rb[3], u3.h, s, false);
        }

        float u1 = ch1[0] * rh[0] + ch1[1] * rh[1] + ch1[2] * rh[2];
        float v2[3];
#pragma unroll
        for (int x = 0; x < 3; ++x)
            v2[x] = ch2[x * 3] * rh[0] + ch2[x * 3 + 1] * rh[1] + ch2[x * 3 + 2] * rh[2];
        float w2 = v2[0] * rh[0] + v2[1] * rh[1] + v2[2] * rh[2];

        a0 = fmaf(fc[0], ch0, a0);
        a0 = fmaf(fc[4], u1, a0);
        a0 = fmaf(fc[9], w2, a0);

        float c1 = fc[1] * ch0 + fc[6] * u1;
#pragma unroll
        for (int x = 0; x < 3; ++x)
            a1[x] += c1 * rh[x] + fc[3] * ch1[x] + fc[8] * v2[x];

#pragma unroll
        for (int x = 0; x < 3; ++x) {
            float cx = fc[2] * ch0 * rh[x] + fc[5] * ch1[x] + fc[10] * v2[x];
#pragma unroll
            for (int y = 0; y < 3; ++y)
                a2[x * 3 + y] += cx * rh[y] + fc[7] * ch2[x * 3 + y];
        }
    }

    // ---- coalesced accumulator stores into out regions (acc layout) ----
    const float SC = 0.1f;  // 1/NORM_FACTOR
    out0[(size_t)n * CH + c] = a0 * SC;
#pragma unroll
    for (int x = 0; x < 3; ++x)
        out1[(size_t)n * 192 + x * 64 + c] = a1[x] * SC;
#pragma unroll
    for (int q = 0; q < 9; ++q)
        out2[(size_t)n * 576 + q * 64 + c] = a2[q] * SC;
}

// ---------------------------------------------------------------
// Epilogue way 0: s0 = b0 + acc0 . w0; out0 = node0 + silu(s0)
// wave per E0_APW atoms; lane = c; acc reads are wave-uniform (s_load).
__global__ __launch_bounds__(256, 2) void epi0_kernel(
    float* __restrict__ o0, const float* __restrict__ node0,
    const float* __restrict__ si_w0, const float* __restrict__ si_b0)
{
    int wid = blockIdx.x * 4 + (threadIdx.x >> 6);
    int c = threadIdx.x & 63;

    float w0r[CH];
#pragma unroll
    for (int cc = 0; cc < CH; ++cc) w0r[cc] = si_w0[cc * CH + c];
    float b0 = si_b0[c];

    for (int t = 0; t < E0_APW; ++t) {
        int n = wid * E0_APW + t;
        if (n >= N_ATOMS) break;
        const float* ap = o0 + (size_t)n * CH;   // wave-uniform base

        float p0 = 0.f, p1 = 0.f, p2s = 0.f, p3 = 0.f;
#pragma unroll
        for (int cc = 0; cc < CH; cc += 4) {
            p0 = fmaf(ap[cc + 0], w0r[cc + 0], p0);
            p1 = fmaf(ap[cc + 1], w0r[cc + 1], p1);
            p2s = fmaf(ap[cc + 2], w0r[cc + 2], p2s);
            p3 = fmaf(ap[cc + 3], w0r[cc + 3], p3);
        }
        float s0 = b0 + ((p0 + p1) + (p2s + p3));
        float r0 = s0 / (1.0f + expf(-s0));
        o0[(size_t)n * CH + c] = node0[(size_t)n * CH + c] + r0;
    }
}

// ---------------------------------------------------------------
// Epilogue way 1: s1[x] = acc1[x] . w1; gate by silu(|s1| nl); residual.
__global__ __launch_bounds__(256, 2) void epi1_kernel(
    float* __restrict__ o1, const float* __restrict__ node1,
    const float* __restrict__ si_w1,
    const float* __restrict__ nl_w1, const float* __restrict__ nl_b1)
{
    int wid = blockIdx.x * 4 + (threadIdx.x >> 6);
    int c = threadIdx.x & 63;

    float w1r[CH];
#pragma unroll
    for (int cc = 0; cc < CH; ++cc) w1r[cc] = si_w1[cc * CH + c];
    float nw = nl_w1[c], nb = nl_b1[c];

    for (int t = 0; t < E1_APW; ++t) {
        int n = wid * E1_APW + t;
        if (n >= N_ATOMS) break;
        const float* ap = o1 + (size_t)n * 192;   // wave-uniform base

        float s1[3] = {0.f, 0.f, 0.f};
#pragma unroll
        for (int x = 0; x < 3; ++x)
#pragma unroll
            for (int cc = 0; cc < CH; ++cc)
                s1[x] = fmaf(ap[x * 64 + cc], w1r[cc], s1[x]);

        float n1 = sqrtf(s1[0] * s1[0] + s1[1] * s1[1] + s1[2] * s1[2] + 1e-6f);
        float g1 = n1 * nw + nb;
        float gate1 = g1 / (1.0f + expf(-g1));
#pragma unroll
        for (int x = 0; x < 3; ++x)
            o1[(size_t)n * 192 + c * 3 + x] =
                node1[(size_t)n * 192 + c * 3 + x] + s1[x] * gate1;
    }
}

// ---------------------------------------------------------------
// Epilogue way 2: s2[q] = acc2[q] . w2; gate by silu(|s2| nl); residual.
__global__ __launch_bounds__(256, 2) void epi2_kernel(
    float* __restrict__ o2, const float* __restrict__ node2,
    const float* __restrict__ si_w2,
    const float* __restrict__ nl_w2, const float* __restrict__ nl_b2)
{
    int wid = blockIdx.x * 4 + (threadIdx.x >> 6);
    int c = threadIdx.x & 63;

    float w2r[CH];
#pragma unroll
    for (int cc = 0; cc < CH; ++cc) w2r[cc] = si_w2[cc * CH + c];
    float nw = nl_w2[c], nb = nl_b2[c];

    for (int t = 0; t < E2_APW; ++t) {
        int n = wid * E2_APW + t;
        if (n >= N_ATOMS) break;
        const float* ap = o2 + (size_t)n * 576;   // wave-uniform base

        float s2[9];
#pragma unroll
        for (int q = 0; q < 9; ++q) s2[q] = 0.f;
#pragma unroll
        for (int q = 0; q < 9; ++q)
#pragma unroll
            for (int cc = 0; cc < CH; ++cc)
                s2[q] = fmaf(ap[q * 64 + cc], w2r[cc], s2[q]);

        float n2sq = 1e-6f;
#pragma unroll
        for (int q = 0; q < 9; ++q) n2sq = fmaf(s2[q], s2[q], n2sq);
        float g2 = sqrtf(n2sq) * nw + nb;
        float gate2 = g2 / (1.0f + expf(-g2));
#pragma unroll
        for (int q = 0; q < 9; ++q)
            o2[(size_t)n * 576 + c * 9 + q] =
                node2[(size_t)n * 576 + c * 9 + q] + s2[q] * gate2;
    }
}

extern "C" void kernel_launch(void* const* d_in, const int* in_sizes, int n_in,
                              void* d_out, int out_size, void* d_ws, size_t ws_size,
                              hipStream_t stream) {
    const float* node0 = (const float*)d_in[0];
    const float* node1 = (const float*)d_in[1];
    const float* node2 = (const float*)d_in[2];
    const float* edge0 = (const float*)d_in[3];
    const float* rij   = (const float*)d_in[4];
    const int*   idx_i = (const int*)d_in[5];
    const int*   idx_j = (const int*)d_in[6];
    const float* rbf_w = (const float*)d_in[7];
    const float* si_w0 = (const float*)d_in[8];
    const float* si_b0 = (const float*)d_in[9];
    const float* si_w1 = (const float*)d_in[10];
    const float* si_w2 = (const float*)d_in[11];
    const float* nl_w1 = (const float*)d_in[12];
    const float* nl_b1 = (const float*)d_in[13];
    const float* nl_w2 = (const float*)d_in[14];
    const float* nl_b2 = (const float*)d_in[15];

    float* out = (float*)d_out;
    float* out0 = out;                                   // [A, C]
    float* out1 = out + (size_t)N_ATOMS * CH;            // [A, C, 3]
    float* out2 = out1 + (size_t)N_ATOMS * CH * 3;       // [A, C, 3, 3]
    float* oute = out2 + (size_t)N_ATOMS * CH * 9;       // [E, C]

    // workspace layout
    char* ws = (char*)d_ws;
    int* counts  = (int*)ws;                              ws += N_ATOMS * sizeof(int);
    int* cursor  = (int*)ws;                              ws += N_ATOMS * sizeof(int);
    int* offsets = (int*)ws;                              ws += (N_ATOMS + 1) * sizeof(int);
    ws = (char*)(((size_t)ws + 15) & ~(size_t)15);
    int* jlist   = (int*)ws;                              ws += N_EDGES * sizeof(int);
    ws = (char*)(((size_t)ws + 15) & ~(size_t)15);
    float4* ge4  = (float4*)ws;                           // 3 * N_EDGES float4

    hipMemsetAsync(counts, 0, N_ATOMS * sizeof(int), stream);

    hist_kernel<<<(N_EDGES + 255) / 256, 256, 0, stream>>>(idx_i, counts);

    scan_kernel<<<1, 1024, 0, stream>>>(counts, offsets, cursor);

    scatter_geom_kernel<<<(N_EDGES + 255) / 256, 256, 0, stream>>>(
        rij, idx_i, idx_j, cursor, jlist, ge4);

    edge_acc_kernel<<<ATOM_BLOCKS + COPY_BLOCKS, 256, 0, stream>>>(
        node0, node1, node2, jlist, offsets, ge4, rbf_w,
        out0, out1, out2,
        (const float4*)edge0, (float4*)oute);

    epi0_kernel<<<E0_BLOCKS, 256, 0, stream>>>(out0, node0, si_w0, si_b0);
    epi1_kernel<<<E1_BLOCKS, 256, 0, stream>>>(out1, node1, si_w1, nl_w1, nl_b1);
    epi2_kernel<<<E2_BLOCKS, 256, 0, stream>>>(out2, node2, si_w2, nl_w2, nl_b2);
}